// Round 8
// baseline (47.530 us; speedup 1.0000x reference)
//
#include <hip/hip_runtime.h>
#include <hip/hip_fp16.h>

#define NUM_STEPS 96
#define SPLIT 8                      // ray segments (threads) per pixel
#define SPT (NUM_STEPS / SPLIT)      // 12 steps per thread
// CT volume is (1,1,128,128,128) f32 per the reference setup_inputs().
#define VD 128
#define NVOX (VD * VD * VD)
#define VOLH_BYTES ((size_t)NVOX * 8)    // 16 MB packed half4 cells

// ---------------------------------------------------------------------------
// Kernel 1: pack x/z-neighbor taps as 4 x fp16 (8 bytes per cell):
//   cell(z,y,x) = ( v[z,y,x], v[z,y,x+], v[z+,y,x], v[z+,y,x+] ),  n+ = min(n+1,127)
// One trilinear sample = 2 x dwordx2 loads (rows y0, y1).
// Each thread packs 4 consecutive-x cells (vectorized row reads, 32B write).
// ---------------------------------------------------------------------------
__global__ __launch_bounds__(256) void prost_packh_kernel(
    const float* __restrict__ ct, uint2* __restrict__ vol)
{
    const int g  = blockIdx.x * 256 + threadIdx.x;  // 0 .. NVOX/4 - 1
    const int xq = g & 31;
    const int y  = (g >> 5) & 127;
    const int z  = g >> 12;
    const int x  = xq << 2;
    const int zp = min(z + 1, VD - 1);

    const float* r0 = ct + (z  << 14) + (y << 7);
    const float* r1 = ct + (zp << 14) + (y << 7);

    const float4 f0 = *reinterpret_cast<const float4*>(r0 + x);
    const float4 f1 = *reinterpret_cast<const float4*>(r1 + x);
    const float  e0 = r0[min(x + 4, VD - 1)];
    const float  e1 = r1[min(x + 4, VD - 1)];

    const float a0[5] = {f0.x, f0.y, f0.z, f0.w, e0};
    const float a1[5] = {f1.x, f1.y, f1.z, f1.w, e1};

    unsigned int c[8];
    #pragma unroll
    for (int j = 0; j < 4; ++j) {
        const __half2 lo = __floats2half2_rn(a0[j], a0[j + 1]); // (v, v[x+])
        const __half2 hi = __floats2half2_rn(a1[j], a1[j + 1]); // (v[z+], v[x+z+])
        c[2 * j]     = *reinterpret_cast<const unsigned int*>(&lo);
        c[2 * j + 1] = *reinterpret_cast<const unsigned int*>(&hi);
    }

    uint4* dst = reinterpret_cast<uint4*>(vol + (size_t)g * 4);
    dst[0] = make_uint4(c[0], c[1], c[2], c[3]);
    dst[1] = make_uint4(c[4], c[5], c[6], c[7]);
}

// ---------------------------------------------------------------------------
// Shared per-thread setup (pose -> folded affine, dmin/dmax, ray dir)
// ---------------------------------------------------------------------------
__device__ __forceinline__ void prost_setup(
    const float* __restrict__ pose, const float* __restrict__ corner,
    const float* __restrict__ param, int h, int w, int H, int W,
    float& Ax, float& Bx, float& Ay, float& By, float& Az, float& Bz,
    float& dmin, float& step)
{
    const float rx = pose[0], ry = pose[1], rz = pose[2];
    const float tx = pose[3], ty = pose[4], tz = pose[5];
    const float cx = cosf(rx), sx = sinf(rx);
    const float cy = cosf(ry), sy = sinf(ry);
    const float cz = cosf(rz), sz = sinf(rz);

    const float r00 = cz * cy;
    const float r01 = -sz * cx + cz * sy * sx;
    const float r02 = sz * sx + cz * sy * cx;
    const float r10 = sz * cy;
    const float r11 = cz * cx + sz * sy * sx;
    const float r12 = -cz * sx + sz * sy * cx;
    const float r20 = -sy;
    const float r21 = cy * sx;
    const float r22 = cy * cx;

    const float t0 = r00 * tx + r01 * ty + r02 * tz;
    const float t1 = r10 * tx + r11 * ty + r12 * tz;
    const float t2 = r20 * tx + r21 * ty + r22 * tz;

    const float src = param[0];
    const float det = param[1];
    const float pix = param[2];

    float dmax = -1e30f;
    dmin = 1e30f;
    #pragma unroll
    for (int c = 0; c < 8; ++c) {
        const float px = corner[c * 3 + 0] - t0;
        const float py = corner[c * 3 + 1] - t1;
        const float pz = corner[c * 3 + 2] - t2;
        const float ix = r00 * px + r01 * py + r02 * pz;
        const float iy = r10 * px + r11 * py + r12 * pz;
        float iz = r20 * px + r21 * py + r22 * pz;
        iz = src - iz;
        const float d = sqrtf(ix * ix + iy * iy + iz * iz);
        dmin = fminf(dmin, d);
        dmax = fmaxf(dmax, d);
    }

    const float ys = ((float)h - (float)(H - 1) * 0.5f) * pix;
    const float xs = ((float)w - (float)(W - 1) * 0.5f) * pix;
    const float dz = -det;
    const float invn = 1.0f / sqrtf(xs * xs + ys * ys + dz * dz);
    const float nx = xs * invn;
    const float ny = ys * invn;
    const float nz = dz * invn;

    Ax = 64.0f * (r00 * nx + r01 * ny + r02 * nz);
    Bx = 64.0f * (r02 * src + t0) + 64.0f;
    Ay = 64.0f * (r10 * nx + r11 * ny + r12 * nz);
    By = 64.0f * (r12 * src + t1) + 64.0f;
    Az = 64.0f * (r20 * nx + r21 * ny + r22 * nz);
    Bz = 64.0f * (r22 * src + t2) + 64.0f;

    step = (dmax - dmin) / (float)(NUM_STEPS - 1);
}

// ---------------------------------------------------------------------------
// Kernel 2 (fast path): 2 x dwordx2 loads per sample, XCD-chunked swizzle,
// 8 blocks/CU (32 waves/CU).
// ---------------------------------------------------------------------------
__global__ __launch_bounds__(256, 8) void prost_fwd_h4_kernel(
    const uint2* __restrict__ vol,
    const float* __restrict__ pose,
    const float* __restrict__ corner,
    const float* __restrict__ param,
    const int* __restrict__ Hp,
    const int* __restrict__ Wp,
    float* __restrict__ out,
    int n)
{
    // XCD-chunked swizzle: dispatch round-robins blocks across the 8 XCDs, so
    // give block `bid` the work chunk (bid&7)*C + bid/8 -> each XCD works a
    // contiguous 32-row image slab whose ray tube (~3.5 MB packed) fits its L2.
    const int nblk = gridDim.x;
    int bid = blockIdx.x;
    if ((nblk & 7) == 0) {
        const int c = nblk >> 3;
        bid = (bid & 7) * c + (bid >> 3);
    }

    const int tid = threadIdx.x;
    const int idx = bid * 32 + (tid >> 3);   // pixel (8 pixels per wave)
    const int seg = tid & 7;                  // ray eighth
    if (idx >= n) return;

    const int H = *Hp;
    const int W = *Wp;
    const int h = idx / W;
    const int w = idx % W;

    float Ax, Bx, Ay, By, Az, Bz, dmin, step;
    prost_setup(pose, corner, param, h, w, H, W, Ax, Bx, Ay, By, Az, Bz, dmin, step);

    const int m0 = seg * SPT;
    float acc = 0.0f;

    #pragma unroll
    for (int k = 0; k < SPT; ++k) {
        const float d = dmin + step * (float)(m0 + k);
        const float X = Ax * d + Bx;
        const float Y = Ay * d + By;
        const float Z = Az * d + Bz;

        // oob test on UNCLIPPED coords, inclusive upper bound (matches ref)
        const bool inb = (X >= 0.0f) & (X <= 128.0f) &
                         (Y >= 0.0f) & (Y <= 128.0f) &
                         (Z >= 0.0f) & (Z <= 128.0f);

        const float fx = floorf(X), fy = floorf(Y), fz = floorf(Z);
        // clamp corners to [0,127]; weights from CLAMPED corners (matches ref)
        const float x0 = fminf(fmaxf(fx,        0.0f), 127.0f);
        const float x1 = fminf(fmaxf(fx + 1.0f, 0.0f), 127.0f);
        const float y0 = fminf(fmaxf(fy,        0.0f), 127.0f);
        const float y1 = fminf(fmaxf(fy + 1.0f, 0.0f), 127.0f);
        const float z0 = fminf(fmaxf(fz,        0.0f), 127.0f);
        const float z1 = fminf(fmaxf(fz + 1.0f, 0.0f), 127.0f);

        const float wx1 = X - x0, wx0 = x1 - X;
        const float wy1 = Y - y0, wy0 = y1 - Y;
        // oob predication folded into z-weights (covers the low-side clamp
        // cases where packed x+/z+ differ from ref: those are oob anyway)
        const float wz0 = inb ? (z1 - Z) : 0.0f;
        const float wz1 = inb ? (Z - z0) : 0.0f;

        const int base = ((int)z0 << 14) + (int)x0;
        const uint2 qa = vol[base + ((int)y0 << 7)];  // (Ia,Ib | Ie,If)
        const uint2 qb = vol[base + ((int)y1 << 7)];  // (Ic,Id | Ig,Ih)

        const __half2 ab = *reinterpret_cast<const __half2*>(&qa.x);
        const __half2 ef = *reinterpret_cast<const __half2*>(&qa.y);
        const __half2 cd = *reinterpret_cast<const __half2*>(&qb.x);
        const __half2 gh = *reinterpret_cast<const __half2*>(&qb.y);

        const float Ia = __low2float(ab), Ib = __high2float(ab);
        const float Ie = __low2float(ef), If = __high2float(ef);
        const float Ic = __low2float(cd), Id = __high2float(cd);
        const float Ig = __low2float(gh), Ih = __high2float(gh);

        acc += wz0 * (wy0 * (wx0 * Ia + wx1 * Ib) +
                      wy1 * (wx0 * Ic + wx1 * Id)) +
               wz1 * (wy0 * (wx0 * Ie + wx1 * If) +
                      wy1 * (wx0 * Ig + wx1 * Ih));
    }

    // reduce across the 8 segments of each pixel (lanes 8k..8k+7)
    acc += __shfl_xor(acc, 1);
    acc += __shfl_xor(acc, 2);
    acc += __shfl_xor(acc, 4);

    if (seg == 0) out[idx] = acc;
}

// ---------------------------------------------------------------------------
// Fallback (ws too small): round-2 kernel, 8 scalar gathers/step. Known-good.
// ---------------------------------------------------------------------------
__global__ __launch_bounds__(256) void prost_fwd_kernel(
    const float* __restrict__ ct,
    const float* __restrict__ pose,
    const float* __restrict__ corner,
    const float* __restrict__ param,
    const int* __restrict__ Hp,
    const int* __restrict__ Wp,
    float* __restrict__ out,
    int n)
{
    const int gid = blockIdx.x * blockDim.x + threadIdx.x;
    const int idx = gid >> 2;
    const int seg = gid & 3;
    if (idx >= n) return;

    const int H = *Hp;
    const int W = *Wp;
    const int h = idx / W;
    const int w = idx % W;

    float Ax, Bx, Ay, By, Az, Bz, dmin, step;
    prost_setup(pose, corner, param, h, w, H, W, Ax, Bx, Ay, By, Az, Bz, dmin, step);

    const int m0 = seg * (NUM_STEPS / 4);
    float acc = 0.0f;

    #pragma unroll 4
    for (int k = 0; k < NUM_STEPS / 4; ++k) {
        const float d = dmin + step * (float)(m0 + k);
        const float X = Ax * d + Bx;
        const float Y = Ay * d + By;
        const float Z = Az * d + Bz;

        const bool inb = (X >= 0.0f) & (X <= 128.0f) &
                         (Y >= 0.0f) & (Y <= 128.0f) &
                         (Z >= 0.0f) & (Z <= 128.0f);

        const float fx = floorf(X), fy = floorf(Y), fz = floorf(Z);
        const float x0 = fminf(fmaxf(fx,        0.0f), 127.0f);
        const float x1 = fminf(fmaxf(fx + 1.0f, 0.0f), 127.0f);
        const float y0 = fminf(fmaxf(fy,        0.0f), 127.0f);
        const float y1 = fminf(fmaxf(fy + 1.0f, 0.0f), 127.0f);
        const float z0 = fminf(fmaxf(fz,        0.0f), 127.0f);
        const float z1 = fminf(fmaxf(fz + 1.0f, 0.0f), 127.0f);

        const float wx1 = X - x0, wx0 = x1 - X;
        const float wy1 = Y - y0, wy0 = y1 - Y;
        const float wz0 = z1 - Z, wz1 = Z - z0;

        const int ix0 = (int)x0, ix1 = (int)x1;
        const int iy0 = (int)y0, iy1 = (int)y1;
        const int iz0 = (int)z0, iz1 = (int)z1;

        const float* p00 = ct + (iz0 << 14) + (iy0 << 7);
        const float* p01 = ct + (iz0 << 14) + (iy1 << 7);
        const float* p10 = ct + (iz1 << 14) + (iy0 << 7);
        const float* p11 = ct + (iz1 << 14) + (iy1 << 7);

        const float Ia = p00[ix0], Ib = p00[ix1];
        const float Ic = p01[ix0], Id = p01[ix1];
        const float Ie = p10[ix0], If = p10[ix1];
        const float Ig = p11[ix0], Ih = p11[ix1];

        const float s =
            wz0 * (wy0 * (wx0 * Ia + wx1 * Ib) + wy1 * (wx0 * Ic + wx1 * Id)) +
            wz1 * (wy0 * (wx0 * Ie + wx1 * If) + wy1 * (wx0 * Ig + wx1 * Ih));
        acc += inb ? s : 0.0f;
    }

    acc += __shfl_xor(acc, 1);
    acc += __shfl_xor(acc, 2);

    if (seg == 0) out[idx] = acc;
}

extern "C" void kernel_launch(void* const* d_in, const int* in_sizes, int n_in,
                              void* d_out, int out_size, void* d_ws, size_t ws_size,
                              hipStream_t stream) {
    const float* ct     = (const float*)d_in[0];
    // d_in[1] = fixed image, unused by the reference computation
    const float* pose   = (const float*)d_in[2];
    const float* corner = (const float*)d_in[3];
    const float* param  = (const float*)d_in[4];
    const int*   Hp     = (const int*)d_in[5];
    const int*   Wp     = (const int*)d_in[6];
    float* out = (float*)d_out;

    const int n = out_size;                  // H*W pixels

    if (ws_size >= VOLH_BYTES) {
        uint2* vol = (uint2*)d_ws;
        prost_packh_kernel<<<(NVOX / 4) / 256, 256, 0, stream>>>(ct, vol);
        const int blocks = (n * SPLIT + 255) / 256;   // 2048 for 256x256
        prost_fwd_h4_kernel<<<blocks, 256, 0, stream>>>(vol, pose, corner, param,
                                                        Hp, Wp, out, n);
    } else {
        const int total = n * 4;
        prost_fwd_kernel<<<(total + 255) / 256, 256, 0, stream>>>(ct, pose, corner,
                                                                  param, Hp, Wp, out, n);
    }
}

// Round 9
// 43.164 us; speedup vs baseline: 1.1011x; 1.1011x over previous
//
#include <hip/hip_runtime.h>

#define NUM_STEPS 96
#define SPLIT 4                      // in-wave ray segments (lane groups of 4)
#define HALVES 2                     // block-level ray halves
#define SPT (NUM_STEPS / (SPLIT * HALVES))   // 12 steps per thread
#define PIX_PER_BLOCK 64             // 256 threads / SPLIT
// CT volume is (1,1,128,128,128) f32 per the reference setup_inputs().
#define VD 128

__global__ __launch_bounds__(256, 8) void prost_fwd_kernel(
    const float* __restrict__ ct,
    const float* __restrict__ pose,
    const float* __restrict__ corner,
    const float* __restrict__ param,
    const int* __restrict__ Hp,
    const int* __restrict__ Wp,
    float* __restrict__ out,
    int n)
{
    const int tid  = threadIdx.x;
    const int bid  = blockIdx.x;
    const int half = bid & 1;                 // which half of the ray
    const int idx  = (bid >> 1) * PIX_PER_BLOCK + (tid >> 2);  // pixel
    const int seg  = tid & 3;                 // quarter within the half
    if (idx >= n) return;

    const int H = *Hp;
    const int W = *Wp;
    const int h = idx / W;
    const int w = idx % W;

    // ---- pose -> R (Rz@Ry@Rx), t' = R @ t  (recomputed per thread; trivial)
    const float rx = pose[0], ry = pose[1], rz = pose[2];
    const float tx = pose[3], ty = pose[4], tz = pose[5];
    const float cx = cosf(rx), sx = sinf(rx);
    const float cy = cosf(ry), sy = sinf(ry);
    const float cz = cosf(rz), sz = sinf(rz);

    const float r00 = cz * cy;
    const float r01 = -sz * cx + cz * sy * sx;
    const float r02 = sz * sx + cz * sy * cx;
    const float r10 = sz * cy;
    const float r11 = cz * cx + sz * sy * sx;
    const float r12 = -cz * sx + sz * sy * cx;
    const float r20 = -sy;
    const float r21 = cy * sx;
    const float r22 = cy * cx;

    const float t0 = r00 * tx + r01 * ty + r02 * tz;
    const float t1 = r10 * tx + r11 * ty + r12 * tz;
    const float t2 = r20 * tx + r21 * ty + r22 * tz;

    const float src = param[0];
    const float det = param[1];
    const float pix = param[2];

    // ---- ray distance range over the 8 corners; inv(R) = R^T (pure rotation)
    float dmin = 1e30f, dmax = -1e30f;
    #pragma unroll
    for (int c = 0; c < 8; ++c) {
        const float px = corner[c * 3 + 0] - t0;
        const float py = corner[c * 3 + 1] - t1;
        const float pz = corner[c * 3 + 2] - t2;
        const float ix = r00 * px + r01 * py + r02 * pz;
        const float iy = r10 * px + r11 * py + r12 * pz;
        float iz = r20 * px + r21 * py + r22 * pz;
        iz = src - iz;
        const float d = sqrtf(ix * ix + iy * iy + iz * iz);
        dmin = fminf(dmin, d);
        dmax = fmaxf(dmax, d);
    }

    // ---- this pixel's ray direction (normalized)
    const float ys = ((float)h - (float)(H - 1) * 0.5f) * pix;
    const float xs = ((float)w - (float)(W - 1) * 0.5f) * pix;
    const float dz = -det;
    const float invn = 1.0f / sqrtf(xs * xs + ys * ys + dz * dz);
    const float nx = xs * invn;
    const float ny = ys * invn;
    const float nz = dz * invn;

    // ---- fold the affine chain: voxel(d) = A*d + B per axis
    const float Ax = 64.0f * (r00 * nx + r01 * ny + r02 * nz);
    const float Bx = 64.0f * (r02 * src + t0) + 64.0f;
    const float Ay = 64.0f * (r10 * nx + r11 * ny + r12 * nz);
    const float By = 64.0f * (r12 * src + t1) + 64.0f;
    const float Az = 64.0f * (r20 * nx + r21 * ny + r22 * nz);
    const float Bz = 64.0f * (r22 * src + t2) + 64.0f;

    const float step = (dmax - dmin) / (float)(NUM_STEPS - 1);

    const int m0 = (half * SPLIT + seg) * SPT;   // this thread's 12-step window
    float acc = 0.0f;

    #pragma unroll 4
    for (int k = 0; k < SPT; ++k) {
        const float d = dmin + step * (float)(m0 + k);
        const float X = Ax * d + Bx;
        const float Y = Ay * d + By;
        const float Z = Az * d + Bz;

        // oob test on UNCLIPPED coords, inclusive upper bound (matches ref)
        const bool inb = (X >= 0.0f) & (X <= 128.0f) &
                         (Y >= 0.0f) & (Y <= 128.0f) &
                         (Z >= 0.0f) & (Z <= 128.0f);

        const float fx = floorf(X), fy = floorf(Y), fz = floorf(Z);
        // clamp corners to [0,127]; weights from CLAMPED corners (matches ref)
        const float x0 = fminf(fmaxf(fx,        0.0f), 127.0f);
        const float x1 = fminf(fmaxf(fx + 1.0f, 0.0f), 127.0f);
        const float y0 = fminf(fmaxf(fy,        0.0f), 127.0f);
        const float y1 = fminf(fmaxf(fy + 1.0f, 0.0f), 127.0f);
        const float z0 = fminf(fmaxf(fz,        0.0f), 127.0f);
        const float z1 = fminf(fmaxf(fz + 1.0f, 0.0f), 127.0f);

        const float wx1 = X - x0, wx0 = x1 - X;
        const float wy1 = Y - y0, wy0 = y1 - Y;
        const float wz0 = z1 - Z, wz1 = Z - z0;

        const int ix0 = (int)x0, ix1 = (int)x1;
        const int iy0 = (int)y0, iy1 = (int)y1;
        const int iz0 = (int)z0, iz1 = (int)z1;

        const float* p00 = ct + (iz0 << 14) + (iy0 << 7);
        const float* p01 = ct + (iz0 << 14) + (iy1 << 7);
        const float* p10 = ct + (iz1 << 14) + (iy0 << 7);
        const float* p11 = ct + (iz1 << 14) + (iy1 << 7);

        // indices always in-bounds (clamped) -> gather unconditionally,
        // predicate only the accumulate (branch-free, loads pipeline)
        const float Ia = p00[ix0], Ib = p00[ix1];
        const float Ic = p01[ix0], Id = p01[ix1];
        const float Ie = p10[ix0], If = p10[ix1];
        const float Ig = p11[ix0], Ih = p11[ix1];

        const float s =
            wz0 * (wy0 * (wx0 * Ia + wx1 * Ib) + wy1 * (wx0 * Ic + wx1 * Id)) +
            wz1 * (wy0 * (wx0 * Ie + wx1 * If) + wy1 * (wx0 * Ig + wx1 * Ih));
        acc += inb ? s : 0.0f;
    }

    // reduce the 4 per-segment partials (lanes 4k..4k+3 share a pixel)
    acc += __shfl_xor(acc, 1);
    acc += __shfl_xor(acc, 2);

    // two half-blocks contribute per pixel; out was zeroed on the stream
    if (seg == 0) atomicAdd(&out[idx], acc);
}

extern "C" void kernel_launch(void* const* d_in, const int* in_sizes, int n_in,
                              void* d_out, int out_size, void* d_ws, size_t ws_size,
                              hipStream_t stream) {
    const float* ct     = (const float*)d_in[0];
    // d_in[1] = fixed image, unused by the reference computation
    const float* pose   = (const float*)d_in[2];
    const float* corner = (const float*)d_in[3];
    const float* param  = (const float*)d_in[4];
    const int*   Hp     = (const int*)d_in[5];
    const int*   Wp     = (const int*)d_in[6];
    float* out = (float*)d_out;

    const int n = out_size;                          // H*W pixels
    // accumulate via atomics -> zero the output first (async, capture-safe)
    hipMemsetAsync(out, 0, (size_t)n * sizeof(float), stream);

    const int blocks = ((n + PIX_PER_BLOCK - 1) / PIX_PER_BLOCK) * HALVES;  // 2048
    prost_fwd_kernel<<<blocks, 256, 0, stream>>>(ct, pose, corner, param,
                                                 Hp, Wp, out, n);
}